// Round 1
// baseline (306.283 us; speedup 1.0000x reference)
//
#include <hip/hip_runtime.h>
#include <hip/hip_bf16.h>

typedef __attribute__((ext_vector_type(8))) short short8;
typedef __attribute__((ext_vector_type(8))) unsigned short ushort8;
typedef __attribute__((ext_vector_type(4))) float f32x4;
typedef __attribute__((ext_vector_type(4))) int int4v;
typedef __attribute__((ext_vector_type(4))) float float4v;

// Problem constants
#define HH 128
#define WW 256
#define CIN_ 128
#define COUT_ 128
#define NTAPS 9

__device__ __forceinline__ float bf2f(unsigned short u) {
  return __builtin_bit_cast(float, ((unsigned int)u) << 16);
}
__device__ __forceinline__ unsigned short f2bf(float f) {
  union { __hip_bfloat16 h; unsigned short u; } v;
  v.h = __float2bfloat16(f);
  return v.u;
}

// ---------------- P0a: T[s][d][ck] = sum_p down_w[d,s*128+p] * weight[p,ck]
// s=0 -> M1 factor (deform), s=1 -> M2 factor (std). ck = c*9 + tap.
__global__ void k_prep_T(const float* __restrict__ down_w,
                         const float* __restrict__ weight,
                         float* __restrict__ T) {
  int e = blockIdx.x * 256 + threadIdx.x;
  if (e >= 2 * 32 * 1152) return;
  int s = e / 36864, r = e % 36864, d = r / 1152, ck = r % 1152;
  float a = 0.f;
  #pragma unroll 4
  for (int p = 0; p < 128; ++p)
    a += down_w[d * 256 + s * 128 + p] * weight[p * 1152 + ck];
  T[e] = a;
}

// ---------------- P0b: effective weights, bf16, layout [tap][o][c]
__global__ void k_prep_W(const float* __restrict__ up_w,
                         const float* __restrict__ weight,
                         const float* __restrict__ T,
                         const float* __restrict__ scale,
                         unsigned short* __restrict__ wdef,
                         unsigned short* __restrict__ wstd) {
  int e = blockIdx.x * 256 + threadIdx.x;
  if (e >= 2 * 9 * 128 * 128) return;
  int s = e / 147456, r = e % 147456;
  int tap = r / 16384, o = (r / 128) % 128, c = r % 128;
  int ck = c * 9 + tap;
  const float* Ts = T + s * 36864;
  float a = 0.f;
  #pragma unroll
  for (int d = 0; d < 32; ++d) a += up_w[o * 32 + d] * Ts[d * 1152 + ck];
  float scl = scale[0];
  if (s == 1) {
    wstd[tap * 16384 + o * 128 + c] = f2bf(weight[o * 1152 + ck] + scl * a);
  } else {
    wdef[tap * 16384 + o * 128 + c] = f2bf(scl * a);
  }
}

// ---------------- P0c: b_eff[o] = bias[o] + scale*sum_d up_w[o,d]*sum_p (dw[d,p]+dw[d,128+p])*bias[p]
__global__ void k_prep_bias(const float* __restrict__ down_w,
                            const float* __restrict__ up_w,
                            const float* __restrict__ bias,
                            const float* __restrict__ scale,
                            float* __restrict__ beff) {
  __shared__ float sd[32];
  int t = threadIdx.x;
  if (t < 32) {
    float a = 0.f;
    for (int p = 0; p < 128; ++p)
      a += (down_w[t * 256 + p] + down_w[t * 256 + 128 + p]) * bias[p];
    sd[t] = a;
  }
  __syncthreads();
  if (t < 128) {
    float a = 0.f;
    #pragma unroll
    for (int d = 0; d < 32; ++d) a += up_w[t * 32 + d] * sd[d];
    beff[t] = bias[t] + scale[0] * a;
  }
}

// ---------------- P1: x NCHW f32 -> NHWC bf16 (LDS transpose tile 32x x 128c)
__global__ __launch_bounds__(256) void k_nhwc(const float* __restrict__ x,
                                              unsigned short* __restrict__ xh) {
  __shared__ float tile[32 * 129];  // stride 129 breaks bank conflicts
  int idx = blockIdx.x;             // b(2) * y(128) * xg(8)
  int b = idx >> 10, rem = idx & 1023;
  int y = rem >> 3, xg = (rem & 7) << 5;
  int tid = threadIdx.x;
  for (int it = tid; it < 32 * 128; it += 256) {
    int c = it >> 5, xi = it & 31;
    tile[xi * 129 + c] = x[(((size_t)b * 128 + c) * 128 + y) * 256 + xg + xi];
  }
  __syncthreads();
  for (int it = tid; it < 32 * 16; it += 256) {
    int xi = it >> 4, cs = it & 15;
    ushort8 v;
    #pragma unroll
    for (int e = 0; e < 8; ++e) v[e] = f2bf(tile[xi * 129 + cs * 8 + e]);
    *(ushort8*)(xh + (((size_t)b * 128 + y) * 256 + xg + xi) * 128 + cs * 8) = v;
  }
}

// ---------------- P2: bilinear metadata per (tap, i, j)
// mo: 4 clipped element offsets (NHWC, b=0, c=0); mw: 4 weights with validity folded.
__global__ void k_meta(const float* __restrict__ offset,
                       int4v* __restrict__ mo, float4v* __restrict__ mw) {
  int e = blockIdx.x * 256 + threadIdx.x;
  if (e >= 9 * 128 * 256) return;
  int k = e >> 15, rem = e & 32767;
  int ii = rem >> 8, jj = rem & 255;
  float dy = offset[(2 * k) * 32768 + rem];
  float dx = offset[(2 * k + 1) * 32768 + rem];
  int ki = k / 3, kj = k % 3;
  float py = (float)(ii - 1 + ki) + dy;
  float px = (float)(jj - 1 + kj) + dx;
  float fy0 = floorf(py), fx0 = floorf(px);
  int y0 = (int)fy0, x0 = (int)fx0;
  float fy = py - fy0, fx = px - fx0;
  float wy0 = 1.f - fy, wx0 = 1.f - fx;
  int ys[2] = {y0, y0 + 1};
  int xs_[2] = {x0, x0 + 1};
  float wy[2] = {wy0, fy}, wx[2] = {wx0, fx};
  int4v o;
  float4v w;
  #pragma unroll
  for (int cy = 0; cy < 2; ++cy) {
    #pragma unroll
    for (int cx = 0; cx < 2; ++cx) {
      int yy = ys[cy], xx = xs_[cx];
      bool valid = (yy >= 0) && (yy < HH) && (xx >= 0) && (xx < WW);
      int yc = min(max(yy, 0), HH - 1), xc = min(max(xx, 0), WW - 1);
      int off = (yc * WW + xc) * CIN_;
      float wv = valid ? wy[cy] * wx[cx] : 0.f;
      int ci = cy * 2 + cx;
      if (ci == 0) { o.x = off; w.x = wv; }
      else if (ci == 1) { o.y = off; w.y = wv; }
      else if (ci == 2) { o.z = off; w.z = wv; }
      else { o.w = off; w.w = wv; }
    }
  }
  mo[e] = o;
  mw[e] = w;
}

// ---------------- bilinear B-fragment build (8 channels per lane)
__device__ __forceinline__ short8 bilin(const unsigned short* __restrict__ xb,
                                        int4v o, float4v w, int ce) {
  ushort8 s0 = *(const ushort8*)(xb + o.x + ce);
  ushort8 s1 = *(const ushort8*)(xb + o.y + ce);
  ushort8 s2 = *(const ushort8*)(xb + o.z + ce);
  ushort8 s3 = *(const ushort8*)(xb + o.w + ce);
  ushort8 r;
  #pragma unroll
  for (int e = 0; e < 8; ++e) {
    float f = w.x * bf2f(s0[e]) + w.y * bf2f(s1[e]) +
              w.z * bf2f(s2[e]) + w.w * bf2f(s3[e]);
    r[e] = f2bf(f);
  }
  return __builtin_bit_cast(short8, r);
}

// ---------------- Main: fused conv + deform-conv implicit GEMM, bf16 MFMA
// Block = 128 out-ch x 64 pixels (one row segment, fixed b,i). 4 waves (2 o-halves x 2 pixel-halves).
__global__ __launch_bounds__(256) void k_main(
    const unsigned short* __restrict__ xh,
    const int4v* __restrict__ mo, const float4v* __restrict__ mw,
    const unsigned short* __restrict__ wstd, const unsigned short* __restrict__ wdef,
    const float* __restrict__ beff, float* __restrict__ out) {
  // x tile: rows i-1..i+1, cols j0-1..j0+64, all 128 c, bf16, XOR-swizzled 16B slots
  __shared__ __align__(16) unsigned short xs[3 * 66 * 128];  // 50688 B

  int t = blockIdx.x;  // 1024 = b(2) * i(128) * jt(4)
  int b = t >> 9, i = (t >> 2) & 127, j0 = (t & 3) << 6;
  int tid = threadIdx.x;
  const unsigned short* xb = xh + (size_t)b * (HH * WW * CIN_);

  for (int it = tid; it < 3 * 66 * 16; it += 256) {
    int cs = it & 15, colr = it >> 4;
    int col = colr % 66, row = colr / 66;
    int gy = i - 1 + row, gx = j0 - 1 + col;
    ushort8 v = {};
    if ((unsigned)gy < (unsigned)HH && (unsigned)gx < (unsigned)WW)
      v = *(const ushort8*)(xb + ((size_t)(gy * WW + gx)) * CIN_ + cs * 8);
    *(ushort8*)((char*)xs + ((row * 66 + col) << 8) + ((cs << 4) ^ ((col & 15) << 4))) = v;
  }
  __syncthreads();

  int lane = tid & 63, wid = tid >> 6;
  int obase = (wid >> 1) << 6;    // 0 or 64
  int pixbase = (wid & 1) << 5;   // 0 or 32
  int lrow = lane & 15, lhi = lane >> 4;

  f32x4 acc[4][2] = {};
  int jg0 = j0 + pixbase + lrow;

  for (int ki = 0; ki < 3; ++ki) {
    for (int kj = 0; kj < 3; ++kj) {
      int tap = ki * 3 + kj;
      int midx = (tap * HH + i) * WW + jg0;
      int4v o0 = mo[midx], o1 = mo[midx + 16];
      float4v w0 = mw[midx], w1 = mw[midx + 16];

      for (int cc = 0; cc < 4; ++cc) {
        // A fragments: Wt[tap][o][c], lane row = lrow, k = lhi*8+e
        const unsigned short* wps = wstd + ((size_t)(tap * 128 + obase + lrow)) * 128 + cc * 32 + lhi * 8;
        const unsigned short* wpd = wdef + ((size_t)(tap * 128 + obase + lrow)) * 128 + cc * 32 + lhi * 8;
        short8 as_[4], ad_[4];
        #pragma unroll
        for (int am = 0; am < 4; ++am) {
          as_[am] = *(const short8*)(wps + am * 16 * 128);
          ad_[am] = *(const short8*)(wpd + am * 16 * 128);
        }
        // B std fragments from LDS (swizzled)
        short8 bs[2];
        #pragma unroll
        for (int bn = 0; bn < 2; ++bn) {
          int col = pixbase + bn * 16 + lrow + kj;
          int lb = ((ki * 66 + col) << 8) + (((cc << 6) + (lhi << 4)) ^ ((col & 15) << 4));
          bs[bn] = *(const short8*)((const char*)xs + lb);
        }
        // B deform fragments: gathered bilinear
        int ce = cc * 32 + lhi * 8;
        short8 bd0 = bilin(xb, o0, w0, ce);
        short8 bd1 = bilin(xb, o1, w1, ce);

        #pragma unroll
        for (int am = 0; am < 4; ++am) {
          acc[am][0] = __builtin_amdgcn_mfma_f32_16x16x32_bf16(as_[am], bs[0], acc[am][0], 0, 0, 0);
          acc[am][1] = __builtin_amdgcn_mfma_f32_16x16x32_bf16(as_[am], bs[1], acc[am][1], 0, 0, 0);
          acc[am][0] = __builtin_amdgcn_mfma_f32_16x16x32_bf16(ad_[am], bd0, acc[am][0], 0, 0, 0);
          acc[am][1] = __builtin_amdgcn_mfma_f32_16x16x32_bf16(ad_[am], bd1, acc[am][1], 0, 0, 0);
        }
      }
    }
  }

  // epilogue: + b_eff, store f32 NCHW
  #pragma unroll
  for (int am = 0; am < 4; ++am) {
    #pragma unroll
    for (int bn = 0; bn < 2; ++bn) {
      int jg = j0 + pixbase + bn * 16 + lrow;
      #pragma unroll
      for (int r = 0; r < 4; ++r) {
        int o = obase + am * 16 + lhi * 4 + r;
        out[(((size_t)b * COUT_ + o) * HH + i) * WW + jg] = acc[am][bn][r] + beff[o];
      }
    }
  }
}

extern "C" void kernel_launch(void* const* d_in, const int* in_sizes, int n_in,
                              void* d_out, int out_size, void* d_ws, size_t ws_size,
                              hipStream_t stream) {
  const float* x      = (const float*)d_in[0];
  const float* offset = (const float*)d_in[1];
  const float* weight = (const float*)d_in[2];
  const float* bias   = (const float*)d_in[3];
  const float* down_w = (const float*)d_in[4];
  const float* up_w   = (const float*)d_in[5];
  const float* scale  = (const float*)d_in[6];
  float* out = (float*)d_out;

  char* ws = (char*)d_ws;
  // layout (16B aligned):
  unsigned short* xh   = (unsigned short*)(ws);              // 16,777,216 B
  int4v* mo            = (int4v*)(ws + 16777216);            //  4,718,592 B
  float4v* mw          = (float4v*)(ws + 21495808);          //  4,718,592 B
  unsigned short* wstd = (unsigned short*)(ws + 26214400);   //    294,912 B
  unsigned short* wdef = (unsigned short*)(ws + 26509312);   //    294,912 B
  float* T             = (float*)(ws + 26804224);            //    294,912 B
  float* beff          = (float*)(ws + 27099136);            //        512 B

  k_prep_T<<<dim3(288), dim3(256), 0, stream>>>(down_w, weight, T);
  k_prep_W<<<dim3(1152), dim3(256), 0, stream>>>(up_w, weight, T, scale, wdef, wstd);
  k_prep_bias<<<dim3(1), dim3(128), 0, stream>>>(down_w, up_w, bias, scale, beff);
  k_nhwc<<<dim3(2048), dim3(256), 0, stream>>>(x, xh);
  k_meta<<<dim3(1152), dim3(256), 0, stream>>>(offset, mo, mw);
  k_main<<<dim3(1024), dim3(256), 0, stream>>>(xh, mo, mw, wstd, wdef, beff, out);
}

// Round 2
// 274.761 us; speedup vs baseline: 1.1147x; 1.1147x over previous
//
#include <hip/hip_runtime.h>
#include <hip/hip_bf16.h>

typedef __attribute__((ext_vector_type(8))) short short8;
typedef __attribute__((ext_vector_type(8))) unsigned short ushort8;
typedef __attribute__((ext_vector_type(4))) float f32x4;
typedef __attribute__((ext_vector_type(4))) int int4v;
typedef __attribute__((ext_vector_type(4))) float float4v;

#define HH 128
#define WW 256
#define CIN_ 128
#define COUT_ 128

__device__ __forceinline__ float bf2f(unsigned short u) {
  return __builtin_bit_cast(float, ((unsigned int)u) << 16);
}
__device__ __forceinline__ unsigned short f2bf(float f) {
  union { __hip_bfloat16 h; unsigned short u; } v;
  v.h = __float2bfloat16(f);
  return v.u;
}

// ---------------- P0a: T[s][d][ck] = sum_p down_w[d,s*128+p] * weight[p,ck]
__global__ void k_prep_T(const float* __restrict__ down_w,
                         const float* __restrict__ weight,
                         float* __restrict__ T) {
  int e = blockIdx.x * 256 + threadIdx.x;
  if (e >= 2 * 32 * 1152) return;
  int s = e / 36864, r = e % 36864, d = r / 1152, ck = r % 1152;
  float a = 0.f;
  #pragma unroll 4
  for (int p = 0; p < 128; ++p)
    a += down_w[d * 256 + s * 128 + p] * weight[p * 1152 + ck];
  T[e] = a;
}

// ---------------- P0b: effective weights, bf16, layout [tap][o][c]
__global__ void k_prep_W(const float* __restrict__ up_w,
                         const float* __restrict__ weight,
                         const float* __restrict__ T,
                         const float* __restrict__ scale,
                         unsigned short* __restrict__ wdef,
                         unsigned short* __restrict__ wstd) {
  int e = blockIdx.x * 256 + threadIdx.x;
  if (e >= 2 * 9 * 128 * 128) return;
  int s = e / 147456, r = e % 147456;
  int tap = r / 16384, o = (r / 128) % 128, c = r % 128;
  int ck = c * 9 + tap;
  const float* Ts = T + s * 36864;
  float a = 0.f;
  #pragma unroll
  for (int d = 0; d < 32; ++d) a += up_w[o * 32 + d] * Ts[d * 1152 + ck];
  float scl = scale[0];
  if (s == 1) {
    wstd[tap * 16384 + o * 128 + c] = f2bf(weight[o * 1152 + ck] + scl * a);
  } else {
    wdef[tap * 16384 + o * 128 + c] = f2bf(scl * a);
  }
}

// ---------------- P0c: effective bias
__global__ void k_prep_bias(const float* __restrict__ down_w,
                            const float* __restrict__ up_w,
                            const float* __restrict__ bias,
                            const float* __restrict__ scale,
                            float* __restrict__ beff) {
  __shared__ float sd[32];
  int t = threadIdx.x;
  if (t < 32) {
    float a = 0.f;
    for (int p = 0; p < 128; ++p)
      a += (down_w[t * 256 + p] + down_w[t * 256 + 128 + p]) * bias[p];
    sd[t] = a;
  }
  __syncthreads();
  if (t < 128) {
    float a = 0.f;
    #pragma unroll
    for (int d = 0; d < 32; ++d) a += up_w[t * 32 + d] * sd[d];
    beff[t] = bias[t] + scale[0] * a;
  }
}

// ---------------- P1: x NCHW f32 -> NHWC bf16
__global__ __launch_bounds__(256) void k_nhwc(const float* __restrict__ x,
                                              unsigned short* __restrict__ xh) {
  __shared__ float tile[32 * 129];
  int idx = blockIdx.x;
  int b = idx >> 10, rem = idx & 1023;
  int y = rem >> 3, xg = (rem & 7) << 5;
  int tid = threadIdx.x;
  for (int it = tid; it < 32 * 128; it += 256) {
    int c = it >> 5, xi = it & 31;
    tile[xi * 129 + c] = x[(((size_t)b * 128 + c) * 128 + y) * 256 + xg + xi];
  }
  __syncthreads();
  for (int it = tid; it < 32 * 16; it += 256) {
    int xi = it >> 4, cs = it & 15;
    ushort8 v;
    #pragma unroll
    for (int e = 0; e < 8; ++e) v[e] = f2bf(tile[xi * 129 + cs * 8 + e]);
    *(ushort8*)(xh + (((size_t)b * 128 + y) * 256 + xg + xi) * 128 + cs * 8) = v;
  }
}

// ---------------- P2: bilinear metadata per (tap, i, j)
__global__ void k_meta(const float* __restrict__ offset,
                       int4v* __restrict__ mo, float4v* __restrict__ mw) {
  int e = blockIdx.x * 256 + threadIdx.x;
  if (e >= 9 * 128 * 256) return;
  int k = e >> 15, rem = e & 32767;
  int ii = rem >> 8, jj = rem & 255;
  float dy = offset[(2 * k) * 32768 + rem];
  float dx = offset[(2 * k + 1) * 32768 + rem];
  int ki = k / 3, kj = k % 3;
  float py = (float)(ii - 1 + ki) + dy;
  float px = (float)(jj - 1 + kj) + dx;
  float fy0 = floorf(py), fx0 = floorf(px);
  int y0 = (int)fy0, x0 = (int)fx0;
  float fy = py - fy0, fx = px - fx0;
  int ys[2] = {y0, y0 + 1};
  int xs_[2] = {x0, x0 + 1};
  float wy[2] = {1.f - fy, fy}, wx[2] = {1.f - fx, fx};
  int4v o;
  float4v w;
  #pragma unroll
  for (int cy = 0; cy < 2; ++cy) {
    #pragma unroll
    for (int cx = 0; cx < 2; ++cx) {
      int yy = ys[cy], xx = xs_[cx];
      bool valid = (yy >= 0) && (yy < HH) && (xx >= 0) && (xx < WW);
      int yc = min(max(yy, 0), HH - 1), xc = min(max(xx, 0), WW - 1);
      int off = (yc * WW + xc) * CIN_;
      float wv = valid ? wy[cy] * wx[cx] : 0.f;
      int ci = cy * 2 + cx;
      if (ci == 0) { o.x = off; w.x = wv; }
      else if (ci == 1) { o.y = off; w.y = wv; }
      else if (ci == 2) { o.z = off; w.z = wv; }
      else { o.w = off; w.w = wv; }
    }
  }
  mo[e] = o;
  mw[e] = w;
}

// ---------------- Main: 18 virtual taps (std+def), double-buffered B tile in LDS
// Block = 128 out-ch x 64 pixels (fixed b,i). 4 waves: (o-half) x (pixel-half).
__global__ __launch_bounds__(256, 4) void k_main(
    const unsigned short* __restrict__ xh,
    const int4v* __restrict__ mo, const float4v* __restrict__ mw,
    const unsigned short* __restrict__ wstd, const unsigned short* __restrict__ wdef,
    const float* __restrict__ beff, float* __restrict__ out) {
  // B tile: [64 pixels][16 slots of 16B], slot XOR-swizzled by (pix&15). Double-buffered.
  __shared__ __align__(16) unsigned short sbuf[2][64 * 128];  // 2 x 16 KB

  int t = blockIdx.x;  // 1024 = b(2) * i(128) * jt(4)
  int b = t >> 9, i = (t >> 2) & 127, j0 = (t & 3) << 6;
  int tid = threadIdx.x;
  const unsigned short* xb = xh + (size_t)b * (HH * WW * CIN_);

  int p = tid & 63;       // staging pixel
  int sg = tid >> 6;      // staging slot-group (4 slots of 16B each)
  int p4 = p & 15;

  auto stage = [&](int v, unsigned short* buf) {
    int tap = v >> 1;
    char* dst = (char*)buf + (p << 8);
    if (v & 1) {
      // deform tap
      int midx = (tap * HH + i) * WW + j0 + p;
      int4v o = mo[midx];
      float4v w = mw[midx];
      #pragma unroll
      for (int q = 0; q < 4; ++q) {
        int slot = sg * 4 + q;
        int ce = slot * 8;
        ushort8 s0 = *(const ushort8*)(xb + o.x + ce);
        ushort8 s1 = *(const ushort8*)(xb + o.y + ce);
        ushort8 s2 = *(const ushort8*)(xb + o.z + ce);
        ushort8 s3 = *(const ushort8*)(xb + o.w + ce);
        ushort8 r;
        #pragma unroll
        for (int e = 0; e < 8; ++e)
          r[e] = f2bf(w.x * bf2f(s0[e]) + w.y * bf2f(s1[e]) +
                      w.z * bf2f(s2[e]) + w.w * bf2f(s3[e]));
        *(ushort8*)(dst + ((slot ^ p4) << 4)) = r;
      }
    } else {
      // std tap: shifted window copy
      int ki = tap / 3, kj = tap % 3;
      int gy = i - 1 + ki, gx = j0 + p - 1 + kj;
      bool ok = ((unsigned)gy < (unsigned)HH) && ((unsigned)gx < (unsigned)WW);
      const unsigned short* src = xb + ((size_t)(gy * WW + gx)) * CIN_;
      #pragma unroll
      for (int q = 0; q < 4; ++q) {
        int slot = sg * 4 + q;
        ushort8 vv = {};
        if (ok) vv = *(const ushort8*)(src + slot * 8);
        *(ushort8*)(dst + ((slot ^ p4) << 4)) = vv;
      }
    }
  };

  int lane = tid & 63, wid = tid >> 6;
  int obase = (wid >> 1) << 6;   // 0 or 64
  int pixbase = (wid & 1) << 5;  // 0 or 32
  int lrow = lane & 15, lhi = lane >> 4;

  f32x4 acc[4][2] = {};

  stage(0, sbuf[0]);
  __syncthreads();

  for (int v = 0; v < 18; ++v) {
    if (v < 17) stage(v + 1, sbuf[(v + 1) & 1]);

    const unsigned short* cur = sbuf[v & 1];
    const unsigned short* wb = ((v & 1) ? wdef : wstd) + (size_t)(v >> 1) * 16384;
    const unsigned short* wrow = wb + (size_t)(obase + lrow) * 128 + lhi * 8;

    #pragma unroll
    for (int cc = 0; cc < 4; ++cc) {
      short8 af[4];
      #pragma unroll
      for (int am = 0; am < 4; ++am)
        af[am] = *(const short8*)(wrow + cc * 32 + am * 16 * 128);
      short8 bf[2];
      #pragma unroll
      for (int bn = 0; bn < 2; ++bn) {
        int pp = pixbase + bn * 16 + lrow;
        bf[bn] = *(const short8*)((const char*)cur + (pp << 8) +
                                  (((cc * 4 + lhi) ^ lrow) << 4));
      }
      #pragma unroll
      for (int am = 0; am < 4; ++am) {
        acc[am][0] = __builtin_amdgcn_mfma_f32_16x16x32_bf16(af[am], bf[0], acc[am][0], 0, 0, 0);
        acc[am][1] = __builtin_amdgcn_mfma_f32_16x16x32_bf16(af[am], bf[1], acc[am][1], 0, 0, 0);
      }
    }
    __syncthreads();
  }

  // epilogue: + b_eff, store f32 NCHW
  #pragma unroll
  for (int am = 0; am < 4; ++am) {
    #pragma unroll
    for (int bn = 0; bn < 2; ++bn) {
      int jg = j0 + pixbase + bn * 16 + lrow;
      #pragma unroll
      for (int r = 0; r < 4; ++r) {
        int o = obase + am * 16 + lhi * 4 + r;
        out[(((size_t)b * COUT_ + o) * HH + i) * WW + jg] = acc[am][bn][r] + beff[o];
      }
    }
  }
}

extern "C" void kernel_launch(void* const* d_in, const int* in_sizes, int n_in,
                              void* d_out, int out_size, void* d_ws, size_t ws_size,
                              hipStream_t stream) {
  const float* x      = (const float*)d_in[0];
  const float* offset = (const float*)d_in[1];
  const float* weight = (const float*)d_in[2];
  const float* bias   = (const float*)d_in[3];
  const float* down_w = (const float*)d_in[4];
  const float* up_w   = (const float*)d_in[5];
  const float* scale  = (const float*)d_in[6];
  float* out = (float*)d_out;

  char* ws = (char*)d_ws;
  unsigned short* xh   = (unsigned short*)(ws);              // 16,777,216 B
  int4v* mo            = (int4v*)(ws + 16777216);            //  4,718,592 B
  float4v* mw          = (float4v*)(ws + 21495808);          //  4,718,592 B
  unsigned short* wstd = (unsigned short*)(ws + 26214400);   //    294,912 B
  unsigned short* wdef = (unsigned short*)(ws + 26509312);   //    294,912 B
  float* T             = (float*)(ws + 26804224);            //    294,912 B
  float* beff          = (float*)(ws + 27099136);            //        512 B

  k_prep_T<<<dim3(288), dim3(256), 0, stream>>>(down_w, weight, T);
  k_prep_W<<<dim3(1152), dim3(256), 0, stream>>>(up_w, weight, T, scale, wdef, wstd);
  k_prep_bias<<<dim3(1), dim3(128), 0, stream>>>(down_w, up_w, bias, scale, beff);
  k_nhwc<<<dim3(2048), dim3(256), 0, stream>>>(x, xh);
  k_meta<<<dim3(1152), dim3(256), 0, stream>>>(offset, mo, mw);
  k_main<<<dim3(1024), dim3(256), 0, stream>>>(xh, mo, mw, wstd, wdef, beff, out);
}

// Round 3
// 120.961 us; speedup vs baseline: 2.5321x; 2.2715x over previous
//
#include <hip/hip_runtime.h>
#include <hip/hip_bf16.h>

typedef __attribute__((ext_vector_type(8))) short short8;
typedef __attribute__((ext_vector_type(8))) unsigned short ushort8;
typedef __attribute__((ext_vector_type(4))) float f32x4;
typedef __attribute__((ext_vector_type(4))) int int4v;
typedef __attribute__((ext_vector_type(4))) float float4v;

#define HH 128
#define WW 256
#define CIN_ 128
#define COUT_ 128

__device__ __forceinline__ float bf2f(unsigned short u) {
  return __builtin_bit_cast(float, ((unsigned int)u) << 16);
}
__device__ __forceinline__ unsigned short f2bf(float f) {
  union { __hip_bfloat16 h; unsigned short u; } v;
  v.h = __float2bfloat16(f);
  return v.u;
}

// ---------------- P0a: T[s][d][ck] = sum_p down_w[d,s*128+p] * weight[p,ck]
__global__ void k_prep_T(const float* __restrict__ down_w,
                         const float* __restrict__ weight,
                         float* __restrict__ T) {
  int e = blockIdx.x * 256 + threadIdx.x;
  if (e >= 2 * 32 * 1152) return;
  int s = e / 36864, r = e % 36864, d = r / 1152, ck = r % 1152;
  float a = 0.f;
  #pragma unroll 4
  for (int p = 0; p < 128; ++p)
    a += down_w[d * 256 + s * 128 + p] * weight[p * 1152 + ck];
  T[e] = a;
}

// ---------------- P0b: effective weights, bf16.
// NEW layout: [tap][cc(=c>>5)][o][c&31]  -> fully coalesced A-fragment loads.
__global__ void k_prep_W(const float* __restrict__ up_w,
                         const float* __restrict__ weight,
                         const float* __restrict__ T,
                         const float* __restrict__ scale,
                         unsigned short* __restrict__ wdef,
                         unsigned short* __restrict__ wstd) {
  int e = blockIdx.x * 256 + threadIdx.x;
  if (e >= 2 * 9 * 128 * 128) return;
  int s = e / 147456, r = e % 147456;
  int tap = r / 16384, o = (r / 128) % 128, c = r % 128;
  int ck = c * 9 + tap;
  const float* Ts = T + s * 36864;
  float a = 0.f;
  #pragma unroll
  for (int d = 0; d < 32; ++d) a += up_w[o * 32 + d] * Ts[d * 1152 + ck];
  float scl = scale[0];
  int idx = ((tap * 4 + (c >> 5)) * 128 + o) * 32 + (c & 31);
  if (s == 1) {
    wstd[idx] = f2bf(weight[o * 1152 + ck] + scl * a);
  } else {
    wdef[idx] = f2bf(scl * a);
  }
}

// ---------------- P0c: effective bias
__global__ void k_prep_bias(const float* __restrict__ down_w,
                            const float* __restrict__ up_w,
                            const float* __restrict__ bias,
                            const float* __restrict__ scale,
                            float* __restrict__ beff) {
  __shared__ float sd[32];
  int t = threadIdx.x;
  if (t < 32) {
    float a = 0.f;
    for (int p = 0; p < 128; ++p)
      a += (down_w[t * 256 + p] + down_w[t * 256 + 128 + p]) * bias[p];
    sd[t] = a;
  }
  __syncthreads();
  if (t < 128) {
    float a = 0.f;
    #pragma unroll
    for (int d = 0; d < 32; ++d) a += up_w[t * 32 + d] * sd[d];
    beff[t] = bias[t] + scale[0] * a;
  }
}

// ---------------- P1: x NCHW f32 -> NHWC bf16
__global__ __launch_bounds__(256) void k_nhwc(const float* __restrict__ x,
                                              unsigned short* __restrict__ xh) {
  __shared__ float tile[32 * 129];
  int idx = blockIdx.x;
  int b = idx >> 10, rem = idx & 1023;
  int y = rem >> 3, xg = (rem & 7) << 5;
  int tid = threadIdx.x;
  for (int it = tid; it < 32 * 128; it += 256) {
    int c = it >> 5, xi = it & 31;
    tile[xi * 129 + c] = x[(((size_t)b * 128 + c) * 128 + y) * 256 + xg + xi];
  }
  __syncthreads();
  for (int it = tid; it < 32 * 16; it += 256) {
    int xi = it >> 4, cs = it & 15;
    ushort8 v;
    #pragma unroll
    for (int e = 0; e < 8; ++e) v[e] = f2bf(tile[xi * 129 + cs * 8 + e]);
    *(ushort8*)(xh + (((size_t)b * 128 + y) * 256 + xg + xi) * 128 + cs * 8) = v;
  }
}

// ---------------- P2: bilinear metadata per (tap, i, j)
__global__ void k_meta(const float* __restrict__ offset,
                       int4v* __restrict__ mo, float4v* __restrict__ mw) {
  int e = blockIdx.x * 256 + threadIdx.x;
  if (e >= 9 * 128 * 256) return;
  int k = e >> 15, rem = e & 32767;
  int ii = rem >> 8, jj = rem & 255;
  float dy = offset[(2 * k) * 32768 + rem];
  float dx = offset[(2 * k + 1) * 32768 + rem];
  int ki = k / 3, kj = k % 3;
  float py = (float)(ii - 1 + ki) + dy;
  float px = (float)(jj - 1 + kj) + dx;
  float fy0 = floorf(py), fx0 = floorf(px);
  int y0 = (int)fy0, x0 = (int)fx0;
  float fy = py - fy0, fx = px - fx0;
  int ys[2] = {y0, y0 + 1};
  int xs_[2] = {x0, x0 + 1};
  float wy[2] = {1.f - fy, fy}, wx[2] = {1.f - fx, fx};
  int4v o;
  float4v w;
  #pragma unroll
  for (int cy = 0; cy < 2; ++cy) {
    #pragma unroll
    for (int cx = 0; cx < 2; ++cx) {
      int yy = ys[cy], xx = xs_[cx];
      bool valid = (yy >= 0) && (yy < HH) && (xx >= 0) && (xx < WW);
      int yc = min(max(yy, 0), HH - 1), xc = min(max(xx, 0), WW - 1);
      int off = (yc * WW + xc) * CIN_;
      float wv = valid ? wy[cy] * wx[cx] : 0.f;
      int ci = cy * 2 + cx;
      if (ci == 0) { o.x = off; w.x = wv; }
      else if (ci == 1) { o.y = off; w.y = wv; }
      else if (ci == 2) { o.z = off; w.z = wv; }
      else { o.w = off; w.w = wv; }
    }
  }
  mo[e] = o;
  mw[e] = w;
}

// ---------------- Main: 18 virtual taps, coalesced staging, dbuf LDS.
// Block = 128 out-ch x 64 pixels (fixed b,i). 4 waves = 4 o-quarters x all pixels.
__global__ __launch_bounds__(256, 4) void k_main(
    const unsigned short* __restrict__ xh,
    const int4v* __restrict__ mo, const float4v* __restrict__ mw,
    const unsigned short* __restrict__ wstd, const unsigned short* __restrict__ wdef,
    const float* __restrict__ beff, float* __restrict__ out) {
  __shared__ __align__(16) unsigned short sbuf[2][64 * 128];  // 2 x 16 KB

  int t = blockIdx.x;  // 1024 = b(2) * i(128) * jt(4)
  int b = t >> 9, i = (t >> 2) & 127, j0 = (t & 3) << 6;
  int tid = threadIdx.x;
  const unsigned short* xb = xh + (size_t)b * (HH * WW * CIN_);

  // staging assignment: 16-lane groups own one pixel; lane-in-group = slot.
  int slot = tid & 15;   // 16B slot within pixel (contiguous across lanes!)
  int pg = tid >> 4;     // pixel-group 0..15

  auto stage = [&](int v, unsigned short* buf) {
    int tap = v >> 1;
    if (v & 1) {
      // deform tap: bilinear gather; 16 consecutive lanes cover one pixel's 256B.
      #pragma unroll
      for (int q = 0; q < 4; ++q) {
        int p = q * 16 + pg;
        int midx = (tap * HH + i) * WW + j0 + p;
        int4v o = mo[midx];
        float4v w = mw[midx];
        int ce = slot * 8;
        ushort8 s0 = *(const ushort8*)(xb + o.x + ce);
        ushort8 s1 = *(const ushort8*)(xb + o.y + ce);
        ushort8 s2 = *(const ushort8*)(xb + o.z + ce);
        ushort8 s3 = *(const ushort8*)(xb + o.w + ce);
        ushort8 r;
        #pragma unroll
        for (int e = 0; e < 8; ++e)
          r[e] = f2bf(w.x * bf2f(s0[e]) + w.y * bf2f(s1[e]) +
                      w.z * bf2f(s2[e]) + w.w * bf2f(s3[e]));
        *(ushort8*)((char*)buf + (p << 8) + ((slot ^ (p & 15)) << 4)) = r;
      }
    } else {
      // std tap: shifted-window copy, fully coalesced (1KB/wave-instr)
      int ki = tap / 3, kj = tap % 3;
      int gy = i - 1 + ki;
      bool oky = (unsigned)gy < (unsigned)HH;
      #pragma unroll
      for (int q = 0; q < 4; ++q) {
        int p = q * 16 + pg;
        int gx = j0 + p - 1 + kj;
        bool ok = oky && ((unsigned)gx < (unsigned)WW);
        ushort8 vv = {};
        if (ok) vv = *(const ushort8*)(xb + (size_t)(gy * WW + gx) * CIN_ + slot * 8);
        *(ushort8*)((char*)buf + (p << 8) + ((slot ^ (p & 15)) << 4)) = vv;
      }
    }
  };

  int lane = tid & 63, wid = tid >> 6;
  int obase = wid << 5;            // wave owns 32 out-channels
  int lrow = lane & 15, lhi = lane >> 4;

  f32x4 acc[2][4] = {};

  stage(0, sbuf[0]);
  __syncthreads();

  for (int v = 0; v < 18; ++v) {
    if (v < 17) stage(v + 1, sbuf[(v + 1) & 1]);

    const unsigned short* cur = sbuf[v & 1];
    const unsigned short* wt = ((v & 1) ? wdef : wstd) + (size_t)(v >> 1) * 16384;

    #pragma unroll
    for (int cc = 0; cc < 4; ++cc) {
      short8 af[2];
      #pragma unroll
      for (int am = 0; am < 2; ++am)
        af[am] = *(const short8*)(wt + ((size_t)(cc * 128 + obase + am * 16 + lrow)) * 32 + lhi * 8);
      short8 bf[4];
      #pragma unroll
      for (int bn = 0; bn < 4; ++bn) {
        int pp = bn * 16 + lrow;
        bf[bn] = *(const short8*)((const char*)cur + (pp << 8) +
                                  (((cc * 4 + lhi) ^ lrow) << 4));
      }
      #pragma unroll
      for (int am = 0; am < 2; ++am)
        #pragma unroll
        for (int bn = 0; bn < 4; ++bn)
          acc[am][bn] = __builtin_amdgcn_mfma_f32_16x16x32_bf16(af[am], bf[bn], acc[am][bn], 0, 0, 0);
    }
    __syncthreads();
  }

  // epilogue: + b_eff, store f32 NCHW
  #pragma unroll
  for (int am = 0; am < 2; ++am) {
    #pragma unroll
    for (int bn = 0; bn < 4; ++bn) {
      int jg = j0 + bn * 16 + lrow;
      #pragma unroll
      for (int r = 0; r < 4; ++r) {
        int o = obase + am * 16 + lhi * 4 + r;
        out[(((size_t)b * COUT_ + o) * HH + i) * WW + jg] = acc[am][bn][r] + beff[o];
      }
    }
  }
}

extern "C" void kernel_launch(void* const* d_in, const int* in_sizes, int n_in,
                              void* d_out, int out_size, void* d_ws, size_t ws_size,
                              hipStream_t stream) {
  const float* x      = (const float*)d_in[0];
  const float* offset = (const float*)d_in[1];
  const float* weight = (const float*)d_in[2];
  const float* bias   = (const float*)d_in[3];
  const float* down_w = (const float*)d_in[4];
  const float* up_w   = (const float*)d_in[5];
  const float* scale  = (const float*)d_in[6];
  float* out = (float*)d_out;

  char* ws = (char*)d_ws;
  unsigned short* xh   = (unsigned short*)(ws);              // 16,777,216 B
  int4v* mo            = (int4v*)(ws + 16777216);            //  4,718,592 B
  float4v* mw          = (float4v*)(ws + 21495808);          //  4,718,592 B
  unsigned short* wstd = (unsigned short*)(ws + 26214400);   //    294,912 B
  unsigned short* wdef = (unsigned short*)(ws + 26509312);   //    294,912 B
  float* T             = (float*)(ws + 26804224);            //    294,912 B
  float* beff          = (float*)(ws + 27099136);            //        512 B

  k_prep_T<<<dim3(288), dim3(256), 0, stream>>>(down_w, weight, T);
  k_prep_W<<<dim3(1152), dim3(256), 0, stream>>>(up_w, weight, T, scale, wdef, wstd);
  k_prep_bias<<<dim3(1), dim3(128), 0, stream>>>(down_w, up_w, bias, scale, beff);
  k_nhwc<<<dim3(2048), dim3(256), 0, stream>>>(x, xh);
  k_meta<<<dim3(1152), dim3(256), 0, stream>>>(offset, mo, mw);
  k_main<<<dim3(1024), dim3(256), 0, stream>>>(xh, mo, mw, wstd, wdef, beff, out);
}